// Round 1
// baseline (4029.740 us; speedup 1.0000x reference)
//
#include <hip/hip_runtime.h>
#include <stdint.h>

#define LCOUNT 6
#define BB 4
#define SS 2048
#define DD 512
#define HH 8
#define DKK 64
#define FFDIM 2048
#define MM (BB*SS)  // 8192 rows

typedef __attribute__((ext_vector_type(8))) __bf16 bf16x8;
typedef __attribute__((ext_vector_type(4))) float f32x4;
typedef unsigned short u16;

__device__ __forceinline__ u16 f2bf(float f) {
  union { float f; uint32_t u; } v; v.f = f;
  uint32_t r = v.u + 0x7FFFu + ((v.u >> 16) & 1u);
  return (u16)(r >> 16);
}
__device__ __forceinline__ float bf2f(u16 u) {
  union { uint32_t u; float f; } v; v.u = ((uint32_t)u) << 16;
  return v.f;
}

__device__ __forceinline__ void gload_lds16(const u16* gsrc, u16* ldst) {
  __builtin_amdgcn_global_load_lds((const __attribute__((address_space(1))) char*)gsrc,
                                   (__attribute__((address_space(3))) char*)ldst, 16, 0, 0);
}

// ---------------------------------------------------------------------------
// fp32 -> bf16 elementwise convert (n divisible by 8)
__global__ __launch_bounds__(256) void f2bf_kernel(const float* __restrict__ in,
                                                   u16* __restrict__ outp, int n) {
  int i = (blockIdx.x * 256 + threadIdx.x) * 8;
  if (i >= n) return;
  float4 a = *(const float4*)&in[i];
  float4 b = *(const float4*)&in[i + 4];
  union { u16 us[8]; uint4 v; } pk;
  pk.us[0] = f2bf(a.x); pk.us[1] = f2bf(a.y); pk.us[2] = f2bf(a.z); pk.us[3] = f2bf(a.w);
  pk.us[4] = f2bf(b.x); pk.us[5] = f2bf(b.y); pk.us[6] = f2bf(b.z); pk.us[7] = f2bf(b.w);
  *(uint4*)&outp[i] = pk.v;
}

// ---------------------------------------------------------------------------
// W [K][N] fp32  ->  Wt [N][K] bf16   (per layer, blockIdx.z = layer)
__global__ __launch_bounds__(256) void wtrans(const float* __restrict__ W,
                                              u16* __restrict__ Wt, int K_, int N_) {
  __shared__ float tile[64 * 65];
  const int l = blockIdx.z;
  const float* Wl = W + (size_t)l * K_ * N_;
  u16* Wtl = Wt + (size_t)l * K_ * N_;
  const int n0 = blockIdx.x * 64, k0 = blockIdx.y * 64;
  const int tid = threadIdx.x;
  const int r = tid >> 2, c4 = (tid & 3) * 16;
#pragma unroll
  for (int j = 0; j < 16; j += 4) {
    float4 v = *(const float4*)&Wl[(size_t)(k0 + r) * N_ + n0 + c4 + j];
    tile[r * 65 + c4 + j + 0] = v.x;
    tile[r * 65 + c4 + j + 1] = v.y;
    tile[r * 65 + c4 + j + 2] = v.z;
    tile[r * 65 + c4 + j + 3] = v.w;
  }
  __syncthreads();
  const int nr = tid >> 2, kc = (tid & 3) * 16;
#pragma unroll
  for (int half = 0; half < 2; ++half) {
    union { u16 us[8]; uint4 v; } pk;
#pragma unroll
    for (int e = 0; e < 8; ++e) pk.us[e] = f2bf(tile[(kc + half * 8 + e) * 65 + nr]);
    *(uint4*)&Wtl[(size_t)(n0 + nr) * K_ + k0 + kc + half * 8] = pk.v;
  }
}

// ---------------------------------------------------------------------------
// GEMM: C[M,N] = A[M,K] @ W[K,N] + bias, W given transposed Wt[N][K].
// bf16 in, fp32 acc, bf16 out. BN=128 fixed, BK=64, 256 threads (2x2 waves).
// LDS XOR-swizzled 16B slots (slot ^= row&7) with pre-swizzled global source.
template <int BMT, bool RELU>
__global__ __launch_bounds__(256)
void gemm_bt(const u16* __restrict__ A, const u16* __restrict__ Bt,
             const float* __restrict__ bias, u16* __restrict__ C,
             int N_, int K_) {
  constexpr int MR = BMT / 32;  // m-fragments per wave
  __shared__ u16 As[BMT * 64];
  __shared__ u16 Bs[128 * 64];
  const int tid = threadIdx.x;
  const int wid = tid >> 6, lane = tid & 63;
  const int l15 = lane & 15, g = lane >> 4;
  const int wr = wid >> 1, wc = wid & 1;
  const int brow = blockIdx.y * BMT;
  const int bcol = blockIdx.x * 128;

  f32x4 acc[MR][4];
#pragma unroll
  for (int m = 0; m < MR; ++m)
#pragma unroll
    for (int n = 0; n < 4; ++n) acc[m][n] = (f32x4){0.f, 0.f, 0.f, 0.f};

  for (int kt = 0; kt < K_; kt += 64) {
    // stage A (BMT/32 rounds) and B (4 rounds); linear LDS dest, swizzled src
#pragma unroll
    for (int r = 0; r < BMT / 32; ++r) {
      int row = r * 32 + wid * 8 + (lane >> 3);
      int slot = (lane & 7) ^ (row & 7);
      gload_lds16(A + (size_t)(brow + row) * K_ + kt + slot * 8,
                  &As[r * 2048 + wid * 512]);
    }
#pragma unroll
    for (int r = 0; r < 4; ++r) {
      int row = r * 32 + wid * 8 + (lane >> 3);
      int slot = (lane & 7) ^ (row & 7);
      gload_lds16(Bt + (size_t)(bcol + row) * K_ + kt + slot * 8,
                  &Bs[r * 2048 + wid * 512]);
    }
    __syncthreads();
#pragma unroll
    for (int ks = 0; ks < 2; ++ks) {
      bf16x8 af[MR], bfr[4];
#pragma unroll
      for (int m = 0; m < MR; ++m) {
        int row = wr * (BMT / 2) + m * 16 + l15;
        int slot = (ks * 4 + g) ^ (row & 7);
        af[m] = *(const bf16x8*)&As[row * 64 + slot * 8];
      }
#pragma unroll
      for (int n = 0; n < 4; ++n) {
        int row = wc * 64 + n * 16 + l15;
        int slot = (ks * 4 + g) ^ (row & 7);
        bfr[n] = *(const bf16x8*)&Bs[row * 64 + slot * 8];
      }
#pragma unroll
      for (int m = 0; m < MR; ++m)
#pragma unroll
        for (int n = 0; n < 4; ++n)
          acc[m][n] = __builtin_amdgcn_mfma_f32_16x16x32_bf16(af[m], bfr[n], acc[m][n], 0, 0, 0);
    }
    __syncthreads();
  }
  // epilogue: bias (+ReLU) + bf16 store. C/D map: col=lane&15, row=(lane>>4)*4+r
#pragma unroll
  for (int n = 0; n < 4; ++n) {
    int col = bcol + wc * 64 + n * 16 + l15;
    float bv = bias ? bias[col] : 0.f;
#pragma unroll
    for (int m = 0; m < MR; ++m) {
#pragma unroll
      for (int r = 0; r < 4; ++r) {
        int rowg = brow + wr * (BMT / 2) + m * 16 + g * 4 + r;
        float v = acc[m][n][r] + bv;
        if (RELU) v = fmaxf(v, 0.f);
        C[(size_t)rowg * N_ + col] = f2bf(v);
      }
    }
  }
}

// ---------------------------------------------------------------------------
// Flash attention, one block per (qblock=64 rows, head, batch). 256 thr, 4 waves.
// Wave w owns q-rows [16w,16w+16). Q/K fragments straight from global (16B,
// K-contiguous since DK=64). Softmax via LDS S-tile. P staged swizzled in LDS.
// V fragments via scalar global loads (correctness-first).
template <bool CAUSAL>
__global__ __launch_bounds__(256)
void attn_kernel(const u16* __restrict__ Qm, const u16* __restrict__ Km,
                 const u16* __restrict__ Vm, u16* __restrict__ Om) {
  __shared__ float Ss[64 * 65];
  __shared__ u16 Ps[64 * 64];
  __shared__ float r_s[64];
  __shared__ float l_s[64];
  const int qb = blockIdx.x, h = blockIdx.y, b = blockIdx.z;
  const int tid = threadIdx.x, wid = tid >> 6, lane = tid & 63;
  const int l15 = lane & 15, g = lane >> 4;
  const int qstart = qb * 64;
  const size_t base = ((size_t)b * SS) * DD + h * DKK;

  bf16x8 qf[2];
#pragma unroll
  for (int ks = 0; ks < 2; ++ks)
    qf[ks] = *(const bf16x8*)&Qm[base + (size_t)(qstart + wid * 16 + l15) * DD + ks * 32 + g * 8];

  f32x4 oacc[4];
#pragma unroll
  for (int nb = 0; nb < 4; ++nb) oacc[nb] = (f32x4){0.f, 0.f, 0.f, 0.f};

  float m_run = -3.0e38f, l_run = 0.f;
  const int srow = tid >> 2, spart = tid & 3;
  const int T = CAUSAL ? (qb + 1) : (SS / 64);

  for (int t = 0; t < T; ++t) {
    const int kstart = t * 64;
    // ---- QK^T ----
    f32x4 sacc[4];
#pragma unroll
    for (int nb = 0; nb < 4; ++nb) sacc[nb] = (f32x4){0.f, 0.f, 0.f, 0.f};
#pragma unroll
    for (int nb = 0; nb < 4; ++nb) {
#pragma unroll
      for (int ks = 0; ks < 2; ++ks) {
        bf16x8 kf = *(const bf16x8*)&Km[base + (size_t)(kstart + nb * 16 + l15) * DD + ks * 32 + g * 8];
        sacc[nb] = __builtin_amdgcn_mfma_f32_16x16x32_bf16(qf[ks], kf, sacc[nb], 0, 0, 0);
      }
    }
    // scale + causal mask + write S
#pragma unroll
    for (int nb = 0; nb < 4; ++nb) {
      int colg = kstart + nb * 16 + l15;
#pragma unroll
      for (int r = 0; r < 4; ++r) {
        int rowl = wid * 16 + g * 4 + r;
        float sv = sacc[nb][r] * 0.125f;
        if (CAUSAL && colg > qstart + rowl) sv = -3.0e38f;
        Ss[rowl * 65 + nb * 16 + l15] = sv;
      }
    }
    __syncthreads();
    // ---- online softmax: thread -> (row=tid>>2, 16 cols at part*16) ----
    {
      float p[16];
      float mx = -3.0e38f;
#pragma unroll
      for (int j = 0; j < 16; ++j) {
        p[j] = Ss[srow * 65 + spart * 16 + j];
        mx = fmaxf(mx, p[j]);
      }
      mx = fmaxf(mx, __shfl_xor(mx, 1));
      mx = fmaxf(mx, __shfl_xor(mx, 2));
      float m_new = fmaxf(m_run, mx);
      float sum = 0.f;
#pragma unroll
      for (int j = 0; j < 16; ++j) { p[j] = __expf(p[j] - m_new); sum += p[j]; }
      sum += __shfl_xor(sum, 1);
      sum += __shfl_xor(sum, 2);
      float resc = __expf(m_run - m_new);
      l_run = l_run * resc + sum;
      m_run = m_new;
      if (spart == 0) r_s[srow] = resc;
#pragma unroll
      for (int jj = 0; jj < 2; ++jj) {
        union { u16 us[8]; uint4 v; } pk;
#pragma unroll
        for (int e = 0; e < 8; ++e) pk.us[e] = f2bf(p[jj * 8 + e]);
        int slot = (spart * 2 + jj) ^ (srow & 7);
        *(uint4*)&Ps[srow * 64 + slot * 8] = pk.v;
      }
    }
    __syncthreads();
    // ---- PV ----
    {
#pragma unroll
      for (int r = 0; r < 4; ++r) {
        float rr = r_s[wid * 16 + g * 4 + r];
#pragma unroll
        for (int nb = 0; nb < 4; ++nb) oacc[nb][r] *= rr;
      }
      bf16x8 pf[2];
#pragma unroll
      for (int ks = 0; ks < 2; ++ks) {
        int row = wid * 16 + l15;
        int slot = (ks * 4 + g) ^ (row & 7);
        pf[ks] = *(const bf16x8*)&Ps[row * 64 + slot * 8];
      }
#pragma unroll
      for (int nb = 0; nb < 4; ++nb) {
#pragma unroll
        for (int ks = 0; ks < 2; ++ks) {
          union { u16 us[8]; bf16x8 v; } vf;
#pragma unroll
          for (int i = 0; i < 8; ++i)
            vf.us[i] = Vm[base + (size_t)(kstart + ks * 32 + g * 8 + i) * DD + nb * 16 + l15];
          oacc[nb] = __builtin_amdgcn_mfma_f32_16x16x32_bf16(pf[ks], vf.v, oacc[nb], 0, 0, 0);
        }
      }
    }
    __syncthreads();
  }
  if (spart == 0) l_s[srow] = l_run;
  __syncthreads();
#pragma unroll
  for (int nb = 0; nb < 4; ++nb) {
#pragma unroll
    for (int r = 0; r < 4; ++r) {
      int rowl = wid * 16 + g * 4 + r;
      float inv = 1.f / l_s[rowl];
      Om[base + (size_t)(qstart + rowl) * DD + nb * 16 + l15] = f2bf(oacc[nb][r] * inv);
    }
  }
}

// ---------------------------------------------------------------------------
// LayerNorm(a + b) * g + beta ; one wave per row of 512.
__global__ __launch_bounds__(256)
void ln_kernel(const u16* __restrict__ A, const u16* __restrict__ Bv,
               const float* __restrict__ gamma, const float* __restrict__ beta,
               u16* __restrict__ out_bf, float* __restrict__ out_f32) {
  const int row = blockIdx.x * 4 + (threadIdx.x >> 6);
  const int lane = threadIdx.x & 63;
  uint4 av = *(const uint4*)&A[(size_t)row * DD + lane * 8];
  uint4 bv = *(const uint4*)&Bv[(size_t)row * DD + lane * 8];
  const u16* au = (const u16*)&av;
  const u16* bu = (const u16*)&bv;
  float z[8], s = 0.f, s2 = 0.f;
#pragma unroll
  for (int j = 0; j < 8; ++j) {
    float x = bf2f(au[j]) + bf2f(bu[j]);
    z[j] = x; s += x; s2 += x * x;
  }
#pragma unroll
  for (int off = 1; off < 64; off <<= 1) {
    s += __shfl_xor(s, off);
    s2 += __shfl_xor(s2, off);
  }
  float mean = s * (1.f / 512.f);
  float var = s2 * (1.f / 512.f) - mean * mean;
  float rs = rsqrtf(var + 1e-5f);
  union { u16 us[8]; uint4 v; } pk;
#pragma unroll
  for (int j = 0; j < 8; ++j) {
    float o = (z[j] - mean) * rs * gamma[lane * 8 + j] + beta[lane * 8 + j];
    pk.us[j] = f2bf(o);
    if (out_f32) out_f32[(size_t)row * DD + lane * 8 + j] = o;
  }
  *(uint4*)&out_bf[(size_t)row * DD + lane * 8] = pk.v;
}

// ---------------------------------------------------------------------------
extern "C" void kernel_launch(void* const* d_in, const int* in_sizes, int n_in,
                              void* d_out, int out_size, void* d_ws, size_t ws_size,
                              hipStream_t stream) {
  const float* x   = (const float*)d_in[0];
  const float* enc = (const float*)d_in[1];
  const float* sa_w[4] = {(const float*)d_in[2], (const float*)d_in[4], (const float*)d_in[6], (const float*)d_in[8]};
  const float* sa_b[4] = {(const float*)d_in[3], (const float*)d_in[5], (const float*)d_in[7], (const float*)d_in[9]};
  const float* ca_w[4] = {(const float*)d_in[10], (const float*)d_in[12], (const float*)d_in[14], (const float*)d_in[16]};
  const float* ca_b[4] = {(const float*)d_in[11], (const float*)d_in[13], (const float*)d_in[15], (const float*)d_in[17]};
  const float* ln_g[3] = {(const float*)d_in[18], (const float*)d_in[20], (const float*)d_in[22]};
  const float* ln_b[3] = {(const float*)d_in[19], (const float*)d_in[21], (const float*)d_in[23]};
  const float* ffw1 = (const float*)d_in[24];
  const float* ffb1 = (const float*)d_in[25];
  const float* ffw2 = (const float*)d_in[26];
  const float* ffb2 = (const float*)d_in[27];

  char* ws = (char*)d_ws;
  size_t o = 0;
  auto take = [&](size_t bytes) {
    void* p = ws + o;
    o += (bytes + 255) & ~(size_t)255;
    return p;
  };
  u16* wT[10];
  for (int i = 0; i < 8; ++i) wT[i] = (u16*)take((size_t)LCOUNT * 512 * 512 * 2);
  wT[8] = (u16*)take((size_t)LCOUNT * 512 * 2048 * 2);   // w1t [F][D]
  wT[9] = (u16*)take((size_t)LCOUNT * 2048 * 512 * 2);   // w2t [D][F]
  u16* Hb  = (u16*)take((size_t)MM * 512 * 2);
  u16* Eb  = (u16*)take((size_t)MM * 512 * 2);
  u16* Qb  = (u16*)take((size_t)MM * 512 * 2);
  u16* Kb  = (u16*)take((size_t)MM * 512 * 2);
  u16* Vb  = (u16*)take((size_t)MM * 512 * 2);
  u16* Ab  = (u16*)take((size_t)MM * 512 * 2);
  u16* Pb  = (u16*)take((size_t)MM * 512 * 2);
  u16* X1b = (u16*)take((size_t)MM * 512 * 2);
  u16* Yb  = (u16*)take((size_t)MM * 512 * 2);
  u16* Fb  = (u16*)take((size_t)MM * 2048 * 2);

  f2bf_kernel<<<2048, 256, 0, stream>>>(x, Hb, MM * 512);
  f2bf_kernel<<<2048, 256, 0, stream>>>(enc, Eb, MM * 512);
  for (int i = 0; i < 4; ++i) {
    wtrans<<<dim3(8, 8, LCOUNT), 256, 0, stream>>>(sa_w[i], wT[i], 512, 512);
    wtrans<<<dim3(8, 8, LCOUNT), 256, 0, stream>>>(ca_w[i], wT[4 + i], 512, 512);
  }
  wtrans<<<dim3(32, 8, LCOUNT), 256, 0, stream>>>(ffw1, wT[8], 512, 2048);
  wtrans<<<dim3(8, 32, LCOUNT), 256, 0, stream>>>(ffw2, wT[9], 2048, 512);

  for (int l = 0; l < LCOUNT; ++l) {
    const size_t w512 = (size_t)l * 512 * 512;
    const size_t wff = (size_t)l * 512 * 2048;
    // --- masked self-attention ---
    gemm_bt<64, false><<<dim3(4, MM / 64), 256, 0, stream>>>(Hb, wT[0] + w512, sa_b[0] + l * 512, Qb, 512, 512);
    gemm_bt<64, false><<<dim3(4, MM / 64), 256, 0, stream>>>(Hb, wT[1] + w512, sa_b[1] + l * 512, Kb, 512, 512);
    gemm_bt<64, false><<<dim3(4, MM / 64), 256, 0, stream>>>(Hb, wT[2] + w512, sa_b[2] + l * 512, Vb, 512, 512);
    attn_kernel<true><<<dim3(32, 8, 4), 256, 0, stream>>>(Qb, Kb, Vb, Ab);
    gemm_bt<64, false><<<dim3(4, MM / 64), 256, 0, stream>>>(Ab, wT[3] + w512, sa_b[3] + l * 512, Pb, 512, 512);
    ln_kernel<<<MM / 4, 256, 0, stream>>>(Hb, Pb, ln_g[0] + l * 512, ln_b[0] + l * 512, X1b, nullptr);
    // --- cross-attention (residual from block input Hb, per source) ---
    gemm_bt<64, false><<<dim3(4, MM / 64), 256, 0, stream>>>(X1b, wT[4] + w512, ca_b[0] + l * 512, Qb, 512, 512);
    gemm_bt<64, false><<<dim3(4, MM / 64), 256, 0, stream>>>(Eb, wT[5] + w512, ca_b[1] + l * 512, Kb, 512, 512);
    gemm_bt<64, false><<<dim3(4, MM / 64), 256, 0, stream>>>(Eb, wT[6] + w512, ca_b[2] + l * 512, Vb, 512, 512);
    attn_kernel<false><<<dim3(32, 8, 4), 256, 0, stream>>>(Qb, Kb, Vb, Ab);
    gemm_bt<64, false><<<dim3(4, MM / 64), 256, 0, stream>>>(Ab, wT[7] + w512, ca_b[3] + l * 512, Pb, 512, 512);
    ln_kernel<<<MM / 4, 256, 0, stream>>>(Hb, Pb, ln_g[1] + l * 512, ln_b[1] + l * 512, Yb, nullptr);
    // --- FFN (residual from X1b, per source) ---
    gemm_bt<128, true><<<dim3(16, MM / 128), 256, 0, stream>>>(Yb, wT[8] + wff, ffb1 + l * 2048, Fb, 2048, 512);
    gemm_bt<64, false><<<dim3(4, MM / 64), 256, 0, stream>>>(Fb, wT[9] + wff, ffb2 + l * 512, Pb, 512, 2048);
    ln_kernel<<<MM / 4, 256, 0, stream>>>(X1b, Pb, ln_g[2] + l * 512, ln_b[2] + l * 512, Hb,
                                          (l == LCOUNT - 1) ? (float*)d_out : nullptr);
  }
}